// Round 1
// baseline (2045.809 us; speedup 1.0000x reference)
//
#include <hip/hip_runtime.h>
#include <hip/hip_bf16.h>
#include <math.h>

#define DIMQ 256
#define HID 512
#define HEADS 8
#define HD 32
#define BATCH 16
#define SEQ 4096
#define EPS 1e-5f
#define QK_SCALE 0.17677669529663687f   // 1/sqrt(32), folded into q

typedef __hip_bfloat16 bf16;

__device__ __forceinline__ float wave_sum(float v) {
#pragma unroll
  for (int off = 1; off < 64; off <<= 1) v += __shfl_xor(v, off, 64);
  return v;
}

// ---------------------------------------------------------------------------
// K0: Q = LN(query_param) @ wq + bq, scaled by 1/sqrt(32). Batch-independent.
// grid 256 (one block per row), block 256.
// ---------------------------------------------------------------------------
__global__ __launch_bounds__(256)
void qgen_kernel(const float* __restrict__ qp, const float* __restrict__ g,
                 const float* __restrict__ b, const float* __restrict__ wq,
                 const float* __restrict__ bq, float* __restrict__ qbuf) {
  __shared__ float row[DIMQ];
  __shared__ float red[4];
  const int i = blockIdx.x;
  const int t = threadIdx.x;
  const int lane = t & 63, wid = t >> 6;

  float v = qp[i * DIMQ + t];
  float s = wave_sum(v);
  if (lane == 0) red[wid] = s;
  __syncthreads();
  float mean = (red[0] + red[1] + red[2] + red[3]) * (1.0f / DIMQ);
  float d = v - mean;
  float s2 = wave_sum(d * d);
  __syncthreads();
  if (lane == 0) red[wid] = s2;
  __syncthreads();
  float var = (red[0] + red[1] + red[2] + red[3]) * (1.0f / DIMQ);
  float rs = rsqrtf(var + EPS);
  row[t] = d * rs * g[t] + b[t];
  __syncthreads();

  float acc = bq[t];
  for (int dd = 0; dd < DIMQ; ++dd) acc += row[dd] * wq[dd * DIMQ + t];
  qbuf[i * DIMQ + t] = acc * QK_SCALE;
}

// ---------------------------------------------------------------------------
// KF: fused per-token pipeline. 32 tokens/block, 256 threads.
//   x -> h1(128) -> h2(512) -> h3(512) -> LN -> @wk|wv + bias -> kvp
// Tokens 0..65535 are X (k path), 65536..131071 are Y (v path).
// LDS: h1 (bf16 32x128), tile (bf16 32x516: h2 then LN'd KV). ~41 KB.
// ---------------------------------------------------------------------------
__global__ __launch_bounds__(256)
void token_kernel(const float* __restrict__ input,
                  const float* __restrict__ w1, const float* __restrict__ b1,
                  const float* __restrict__ w2, const float* __restrict__ b2,
                  const float* __restrict__ w3, const float* __restrict__ b3,
                  const float* __restrict__ lkg, const float* __restrict__ lkb,
                  const float* __restrict__ lvg, const float* __restrict__ lvb,
                  const float* __restrict__ wk, const float* __restrict__ bk,
                  const float* __restrict__ wv, const float* __restrict__ bv,
                  float* __restrict__ kvp) {
  __shared__ bf16 h1s[32 * 128];
  __shared__ bf16 tile[32 * 516];   // stride 516 to break bank alignment
  __shared__ float xs[32];
  const int tid = threadIdx.x;
  const int tokbase = blockIdx.x * 32;
  const int side = tokbase >> 16;   // 0 = X/k, 1 = Y/v (blocks never straddle)

  if (tid < 32) {
    int tok = tokbase + tid;
    xs[tid] = input[(tok & 65535) * 2 + side];
  }
  __syncthreads();

  // h1[t][i] = leaky(x_t * w1_i + b1_i)
  for (int idx = tid; idx < 32 * 128; idx += 256) {
    int t = idx >> 7, i = idx & 127;
    float h = xs[t] * w1[i] + b1[i];
    h1s[idx] = __float2bfloat16(h >= 0.f ? h : 0.01f * h);
  }
  __syncthreads();

  const int jj = tid & 63;   // col group: cols jj*8 .. jj*8+7   (wave lane)
  const int tt = tid >> 6;   // token group: tokens tt*8 .. tt*8+7 (wave id)

  // ---- h2 = leaky(h1 @ w2 + b2) -> tile (bf16) ----
  {
    float acc[8][8];
#pragma unroll
    for (int u = 0; u < 8; ++u)
#pragma unroll
      for (int w = 0; w < 8; ++w) acc[u][w] = 0.f;

    for (int j = 0; j < 128; ++j) {
      float4 bA = *(const float4*)(w2 + j * HID + jj * 8);
      float4 bB = *(const float4*)(w2 + j * HID + jj * 8 + 4);
      float a[8];
#pragma unroll
      for (int u = 0; u < 8; ++u)
        a[u] = __bfloat162float(h1s[(tt * 8 + u) * 128 + j]);
#pragma unroll
      for (int u = 0; u < 8; ++u) {
        acc[u][0] += a[u] * bA.x; acc[u][1] += a[u] * bA.y;
        acc[u][2] += a[u] * bA.z; acc[u][3] += a[u] * bA.w;
        acc[u][4] += a[u] * bB.x; acc[u][5] += a[u] * bB.y;
        acc[u][6] += a[u] * bB.z; acc[u][7] += a[u] * bB.w;
      }
    }
    float bb[8];
#pragma unroll
    for (int w = 0; w < 8; ++w) bb[w] = b2[jj * 8 + w];
#pragma unroll
    for (int u = 0; u < 8; ++u)
#pragma unroll
      for (int w = 0; w < 8; ++w) {
        float v = acc[u][w] + bb[w];
        v = v >= 0.f ? v : 0.01f * v;
        tile[(tt * 8 + u) * 516 + jj * 8 + w] = __float2bfloat16(v);
      }
  }
  __syncthreads();

  // ---- h3 = tile @ w3 + b3, then LayerNorm (per token, wave-local) ----
  {
    float acc[8][8];
#pragma unroll
    for (int u = 0; u < 8; ++u)
#pragma unroll
      for (int w = 0; w < 8; ++w) acc[u][w] = 0.f;

    for (int j = 0; j < HID; ++j) {
      float4 bA = *(const float4*)(w3 + j * HID + jj * 8);
      float4 bB = *(const float4*)(w3 + j * HID + jj * 8 + 4);
      float a[8];
#pragma unroll
      for (int u = 0; u < 8; ++u)
        a[u] = __bfloat162float(tile[(tt * 8 + u) * 516 + j]);
#pragma unroll
      for (int u = 0; u < 8; ++u) {
        acc[u][0] += a[u] * bA.x; acc[u][1] += a[u] * bA.y;
        acc[u][2] += a[u] * bA.z; acc[u][3] += a[u] * bA.w;
        acc[u][4] += a[u] * bB.x; acc[u][5] += a[u] * bB.y;
        acc[u][6] += a[u] * bB.z; acc[u][7] += a[u] * bB.w;
      }
    }
    float bb[8], gg[8], bl[8];
    const float* gv = side ? lvg : lkg;
    const float* bev = side ? lvb : lkb;
#pragma unroll
    for (int w = 0; w < 8; ++w) {
      bb[w] = b3[jj * 8 + w];
      gg[w] = gv[jj * 8 + w];
      bl[w] = bev[jj * 8 + w];
    }
    __syncthreads();   // all waves done reading h2 tile before overwrite

    // tokens tt*8+u are held entirely by wave tt (lanes = col groups)
#pragma unroll
    for (int u = 0; u < 8; ++u) {
      float s = 0.f;
#pragma unroll
      for (int w = 0; w < 8; ++w) { acc[u][w] += bb[w]; s += acc[u][w]; }
      s = wave_sum(s);
      float mu = s * (1.0f / HID);
      float d2 = 0.f;
#pragma unroll
      for (int w = 0; w < 8; ++w) { float d = acc[u][w] - mu; d2 += d * d; }
      d2 = wave_sum(d2);
      float rs = rsqrtf(d2 * (1.0f / HID) + EPS);
#pragma unroll
      for (int w = 0; w < 8; ++w)
        tile[(tt * 8 + u) * 516 + jj * 8 + w] =
            __float2bfloat16((acc[u][w] - mu) * rs * gg[w] + bl[w]);
    }
  }
  __syncthreads();

  // ---- k/v projection: kvp[t] = KV[t] @ (wk|wv) + (bk|bv), fp32 out ----
  {
    const int jj2 = tid & 31;   // cols jj2*8 .. +7  (256 cols)
    const int tt2 = tid >> 5;   // tokens tt2*4 .. +3
    const float* W = side ? wv : wk;
    const float* bias = side ? bv : bk;
    float acc[4][8];
    float bi[8];
#pragma unroll
    for (int w = 0; w < 8; ++w) bi[w] = bias[jj2 * 8 + w];
#pragma unroll
    for (int u = 0; u < 4; ++u)
#pragma unroll
      for (int w = 0; w < 8; ++w) acc[u][w] = bi[w];

    for (int i = 0; i < HID; ++i) {
      float4 bA = *(const float4*)(W + i * DIMQ + jj2 * 8);
      float4 bB = *(const float4*)(W + i * DIMQ + jj2 * 8 + 4);
      float a[4];
#pragma unroll
      for (int u = 0; u < 4; ++u)
        a[u] = __bfloat162float(tile[(tt2 * 4 + u) * 516 + i]);
#pragma unroll
      for (int u = 0; u < 4; ++u) {
        acc[u][0] += a[u] * bA.x; acc[u][1] += a[u] * bA.y;
        acc[u][2] += a[u] * bA.z; acc[u][3] += a[u] * bA.w;
        acc[u][4] += a[u] * bB.x; acc[u][5] += a[u] * bB.y;
        acc[u][6] += a[u] * bB.z; acc[u][7] += a[u] * bB.w;
      }
    }
#pragma unroll
    for (int u = 0; u < 4; ++u)
#pragma unroll
      for (int w = 0; w < 8; ++w)
        kvp[(tokbase + tt2 * 4 + u) * DIMQ + jj2 * 8 + w] = acc[u][w];
  }
}

// ---------------------------------------------------------------------------
// K4: flash attention partials. grid (chunk=8, h=8, b=16), block 128.
// Each thread owns q-rows tid and tid+128; online softmax over 512 n.
// ---------------------------------------------------------------------------
__global__ __launch_bounds__(128)
void attn_kernel(const float* __restrict__ qbuf, const float* __restrict__ kvp,
                 float* __restrict__ part) {
  __shared__ float kt[64 * 32];
  __shared__ float vt[64 * 32];
  const int tid = threadIdx.x;
  const int chunk = blockIdx.x, h = blockIdx.y, b = blockIdx.z;

  float qreg[2][32];
#pragma unroll
  for (int rr = 0; rr < 2; ++rr) {
    int r = tid + rr * 128;
    for (int d = 0; d < 32; ++d) qreg[rr][d] = qbuf[r * DIMQ + h * 32 + d];
  }
  float m[2] = {-1e30f, -1e30f};
  float l[2] = {0.f, 0.f};
  float o[2][32];
#pragma unroll
  for (int rr = 0; rr < 2; ++rr)
    for (int d = 0; d < 32; ++d) o[rr][d] = 0.f;

  const int kbase = (b * SEQ + chunk * 512) * DIMQ + h * 32;
  const int vbase = ((65536 + b * SEQ) + chunk * 512) * DIMQ + h * 32;

  for (int ntile = 0; ntile < 8; ++ntile) {
    for (int idx = tid; idx < 2048; idx += 128) {
      int row = idx >> 5, d = idx & 31;
      kt[idx] = kvp[kbase + (ntile * 64 + row) * DIMQ + d];
      vt[idx] = kvp[vbase + (ntile * 64 + row) * DIMQ + d];
    }
    __syncthreads();
    for (int nn = 0; nn < 64; ++nn) {
      float k8[32];
      {
        const float4* kr = (const float4*)(kt + nn * 32);
#pragma unroll
        for (int q4 = 0; q4 < 8; ++q4) {
          float4 t4 = kr[q4];
          k8[q4 * 4 + 0] = t4.x; k8[q4 * 4 + 1] = t4.y;
          k8[q4 * 4 + 2] = t4.z; k8[q4 * 4 + 3] = t4.w;
        }
      }
      float pc[2];
#pragma unroll
      for (int rr = 0; rr < 2; ++rr) {
        float e = 0.f;
#pragma unroll
        for (int d = 0; d < 32; ++d) e += qreg[rr][d] * k8[d];
        if (e > m[rr]) {                      // rare after warm-up
          float al = __expf(m[rr] - e);
          l[rr] *= al;
#pragma unroll
          for (int d = 0; d < 32; ++d) o[rr][d] *= al;
          m[rr] = e;
        }
        float p = __expf(e - m[rr]);
        l[rr] += p;
        pc[rr] = p;
      }
      {
        const float4* vr = (const float4*)(vt + nn * 32);
#pragma unroll
        for (int q4 = 0; q4 < 8; ++q4) {
          float4 t4 = vr[q4];
          int d = q4 * 4;
          o[0][d + 0] += pc[0] * t4.x; o[1][d + 0] += pc[1] * t4.x;
          o[0][d + 1] += pc[0] * t4.y; o[1][d + 1] += pc[1] * t4.y;
          o[0][d + 2] += pc[0] * t4.z; o[1][d + 2] += pc[1] * t4.z;
          o[0][d + 3] += pc[0] * t4.w; o[1][d + 3] += pc[1] * t4.w;
        }
      }
    }
    __syncthreads();
  }

  const int pb = (((b * 8 + h) * 8 + chunk) * 256) * 34;
#pragma unroll
  for (int rr = 0; rr < 2; ++rr) {
    int r = tid + rr * 128;
    float* p = part + pb + r * 34;
    p[0] = m[rr];
    p[1] = l[rr];
    for (int d = 0; d < 32; ++d) p[2 + d] = o[rr][d];
  }
}

// ---------------------------------------------------------------------------
// K5: combine 8 chunk-partials per (b,h,q) row. grid 128, block 256.
// ---------------------------------------------------------------------------
__global__ __launch_bounds__(256)
void combine_kernel(const float* __restrict__ part, float* __restrict__ ao) {
  const int bh = blockIdx.x;
  const int r = threadIdx.x;
  const int b = bh >> 3, h = bh & 7;
  float M = -1e30f;
  for (int c = 0; c < 8; ++c)
    M = fmaxf(M, part[((bh * 8 + c) * 256 + r) * 34]);
  float L = 0.f;
  float o[32];
  for (int d = 0; d < 32; ++d) o[d] = 0.f;
  for (int c = 0; c < 8; ++c) {
    const float* p = part + ((bh * 8 + c) * 256 + r) * 34;
    float w = __expf(p[0] - M);
    L += p[1] * w;
    for (int d = 0; d < 32; ++d) o[d] += p[2 + d] * w;
  }
  float inv = 1.f / L;
  for (int d = 0; d < 32; ++d)
    ao[(b * 256 + r) * 256 + h * 32 + d] = o[d] * inv;
}

// ---------------------------------------------------------------------------
// K6: final projection out = ao @ wo + bo. grid 256 (16 rows each), block 256.
// ---------------------------------------------------------------------------
__global__ __launch_bounds__(256)
void outproj_kernel(const float* __restrict__ ao, const float* __restrict__ wo,
                    const float* __restrict__ bo, float* __restrict__ out) {
  __shared__ float At[16 * 256];
  const int tid = threadIdx.x;
  const int rb = blockIdx.x * 16;
  for (int idx = tid; idx < 16 * 256; idx += 256) At[idx] = ao[rb * 256 + idx];
  __syncthreads();
  float acc[16];
  float bj = bo[tid];
#pragma unroll
  for (int u = 0; u < 16; ++u) acc[u] = bj;
  for (int d = 0; d < 256; ++d) {
    float w = wo[d * 256 + tid];
#pragma unroll
    for (int u = 0; u < 16; ++u) acc[u] += At[u * 256 + d] * w;
  }
#pragma unroll
  for (int u = 0; u < 16; ++u) out[(rb + u) * 256 + tid] = acc[u];
}

// ---------------------------------------------------------------------------
extern "C" void kernel_launch(void* const* d_in, const int* in_sizes, int n_in,
                              void* d_out, int out_size, void* d_ws, size_t ws_size,
                              hipStream_t stream) {
  const float* input = (const float*)d_in[0];
  const float* qp    = (const float*)d_in[1];
  const float* w1    = (const float*)d_in[2];
  const float* b1    = (const float*)d_in[3];
  const float* w2    = (const float*)d_in[4];
  const float* b2    = (const float*)d_in[5];
  const float* w3    = (const float*)d_in[6];
  const float* b3    = (const float*)d_in[7];
  const float* lqg   = (const float*)d_in[8];
  const float* lqb   = (const float*)d_in[9];
  const float* lkg   = (const float*)d_in[10];
  const float* lkb   = (const float*)d_in[11];
  const float* lvg   = (const float*)d_in[12];
  const float* lvb   = (const float*)d_in[13];
  const float* wq    = (const float*)d_in[14];
  const float* bq    = (const float*)d_in[15];
  const float* wk    = (const float*)d_in[16];
  const float* bk    = (const float*)d_in[17];
  const float* wv    = (const float*)d_in[18];
  const float* bv    = (const float*)d_in[19];
  const float* wo    = (const float*)d_in[20];
  const float* bo    = (const float*)d_in[21];
  float* out = (float*)d_out;

  char* ws = (char*)d_ws;
  // kvp: 131072 x 256 fp32 = 134217728 B (k rows first 65536 tokens, then v)
  float* kvp  = (float*)(ws);
  float* qbuf = (float*)(ws + 134217728);                       // 256 KB
  float* part = (float*)(ws + 134217728 + 262144);              // 34.0 MB
  float* ao   = (float*)(ws + 134217728 + 262144 + 35651584);   // 4 MB
  // total ws use ~175 MB

  qgen_kernel<<<256, 256, 0, stream>>>(qp, lqg, lqb, wq, bq, qbuf);
  token_kernel<<<4096, 256, 0, stream>>>(input, w1, b1, w2, b2, w3, b3,
                                         lkg, lkb, lvg, lvb,
                                         wk, bk, wv, bv, kvp);
  attn_kernel<<<dim3(8, 8, 16), 128, 0, stream>>>(qbuf, kvp, part);
  combine_kernel<<<128, 256, 0, stream>>>(part, ao);
  outproj_kernel<<<256, 256, 0, stream>>>(ao, wo, bo, out);
}

// Round 2
// 689.397 us; speedup vs baseline: 2.9675x; 2.9675x over previous
//
#include <hip/hip_runtime.h>
#include <hip/hip_bf16.h>
#include <math.h>

#define DIMQ 256
#define HID 512
#define SEQ 4096
#define EPS 1e-5f
#define QK_SCALE 0.17677669529663687f   // 1/sqrt(32), folded into q

typedef __bf16 bf16_t;
typedef __bf16 bf16x8 __attribute__((ext_vector_type(8)));
typedef float  f32x4  __attribute__((ext_vector_type(4)));

__device__ __forceinline__ f32x4 mfma16(bf16x8 a, bf16x8 b, f32x4 c) {
  return __builtin_amdgcn_mfma_f32_16x16x32_bf16(a, b, c, 0, 0, 0);
}

__device__ __forceinline__ float wave_sum(float v) {
#pragma unroll
  for (int off = 1; off < 64; off <<= 1) v += __shfl_xor(v, off, 64);
  return v;
}

// ---------------------------------------------------------------------------
// Pack fp32 weight [K][N] into bf16 MFMA B-fragment order:
// out[((s*NT + nt)*64 + L)*8 + j] = w[(s*32 + (L>>4)*8 + j)*N + nt*16 + (L&15)]
// so a wave's B-frag load for (K-step s, N-tile nt) is one coalesced 1KB read.
// ---------------------------------------------------------------------------
__global__ __launch_bounds__(256)
void pack_kernel(const float* __restrict__ w, bf16_t* __restrict__ out,
                 int K, int N) {
  int idx = blockIdx.x * 256 + threadIdx.x;
  if (idx >= K * N) return;
  int j = idx & 7;
  int L = (idx >> 3) & 63;
  int f = idx >> 9;
  int NT = N >> 4;
  int nt = f % NT;
  int s = f / NT;
  int k = s * 32 + (L >> 4) * 8 + j;
  int n = nt * 16 + (L & 15);
  out[idx] = (bf16_t)w[k * N + n];
}

// ---------------------------------------------------------------------------
// K0: Q = LN(query_param) @ wq + bq, scaled. Batch-independent. (unchanged)
// ---------------------------------------------------------------------------
__global__ __launch_bounds__(256)
void qgen_kernel(const float* __restrict__ qp, const float* __restrict__ g,
                 const float* __restrict__ b, const float* __restrict__ wq,
                 const float* __restrict__ bq, float* __restrict__ qbuf) {
  __shared__ float row[DIMQ];
  __shared__ float red[4];
  const int i = blockIdx.x;
  const int t = threadIdx.x;
  const int lane = t & 63, wid = t >> 6;

  float v = qp[i * DIMQ + t];
  float s = wave_sum(v);
  if (lane == 0) red[wid] = s;
  __syncthreads();
  float mean = (red[0] + red[1] + red[2] + red[3]) * (1.0f / DIMQ);
  float d = v - mean;
  float s2 = wave_sum(d * d);
  __syncthreads();
  if (lane == 0) red[wid] = s2;
  __syncthreads();
  float var = (red[0] + red[1] + red[2] + red[3]) * (1.0f / DIMQ);
  float rs = rsqrtf(var + EPS);
  row[t] = d * rs * g[t] + b[t];
  __syncthreads();

  float acc = bq[t];
  for (int dd = 0; dd < DIMQ; ++dd) acc += row[dd] * wq[dd * DIMQ + t];
  qbuf[i * DIMQ + t] = acc * QK_SCALE;
}

// ---------------------------------------------------------------------------
// KF: fused per-token pipeline, MFMA version. 32 tokens/block, 256 thr/4 waves.
//   x -> h1(128, LDS bf16) -> h2 = leaky(h1@w2p) (MFMA, LDS bf16)
//     -> h3 = h2@w3p + b3 (MFMA) -> LN (quad-shfl + LDS cross-wave)
//     -> kv = LN@ (wkp|wvp) + bias (MFMA) -> kvp fp32.
// Weights prepacked bf16 in B-frag order (L2-resident).
// A-frag layout: lane holds A[m=lane&15][k=quad*8+j]; C/D: col=lane&15,
// row=quad*4+reg (m89/m120-verified mappings).
// LDS: h1 stride 136 (16B-aligned, 2-way-only conflicts), h2 stride 520.
// ---------------------------------------------------------------------------
#define TOK 32
#define H1S 136
#define H2S 520

__global__ __launch_bounds__(256, 2)
void token_kernel(const float* __restrict__ input,
                  const float* __restrict__ w1, const float* __restrict__ b1,
                  const bf16_t* __restrict__ w2p, const float* __restrict__ b2,
                  const bf16_t* __restrict__ w3p, const float* __restrict__ b3,
                  const float* __restrict__ lkg, const float* __restrict__ lkb,
                  const float* __restrict__ lvg, const float* __restrict__ lvb,
                  const bf16_t* __restrict__ wkp, const float* __restrict__ bk,
                  const bf16_t* __restrict__ wvp, const float* __restrict__ bv,
                  float* __restrict__ kvp) {
  __shared__ bf16_t h1s[TOK * H1S];
  __shared__ bf16_t h2s[TOK * H2S];
  __shared__ float red[TOK * 4];
  __shared__ float xs[TOK];

  const int tid = threadIdx.x;
  const int lane = tid & 63;
  const int wid = tid >> 6;       // wave 0..3
  const int quad = lane >> 4;
  const int l16 = lane & 15;
  const int blockBase = blockIdx.x * TOK;
  const int side = blockBase >> 16;   // 0 = X/k, 1 = Y/v

  if (tid < TOK) xs[tid] = input[((blockBase + tid) & 65535) * 2 + side];
  __syncthreads();

  // ---- stage 0: h1 = leaky(x*w1 + b1), bf16 in LDS ----
  for (int idx = tid; idx < TOK * 128; idx += 256) {
    int t = idx >> 7, i = idx & 127;
    float h = xs[t] * w1[i] + b1[i];
    h1s[t * H1S + i] = (bf16_t)(h >= 0.f ? h : 0.01f * h);
  }
  __syncthreads();

  // ---- stage 1: h2 = leaky(h1 @ w2 + b2), M=32 K=128 N=512, wave: 8 N-tiles
  {
    f32x4 acc[2][8];
#pragma unroll
    for (int j = 0; j < 8; ++j) {
      float bc = b2[(wid * 8 + j) * 16 + l16];
      f32x4 z = {bc, bc, bc, bc};
      acc[0][j] = z; acc[1][j] = z;
    }
    const bf16x8* wf = (const bf16x8*)w2p;
    bf16x8 bb[2][8], aa[2][2];
#pragma unroll
    for (int j = 0; j < 8; ++j) bb[0][j] = wf[(0 * 32 + wid * 8 + j) * 64 + lane];
#pragma unroll
    for (int mt = 0; mt < 2; ++mt)
      aa[0][mt] = *(const bf16x8*)&h1s[(mt * 16 + l16) * H1S + quad * 8];
#pragma unroll
    for (int s = 0; s < 4; ++s) {
      int c = s & 1, nx = c ^ 1;
      if (s < 3) {
#pragma unroll
        for (int j = 0; j < 8; ++j)
          bb[nx][j] = wf[((s + 1) * 32 + wid * 8 + j) * 64 + lane];
#pragma unroll
        for (int mt = 0; mt < 2; ++mt)
          aa[nx][mt] = *(const bf16x8*)&h1s[(mt * 16 + l16) * H1S + (s + 1) * 32 + quad * 8];
      }
#pragma unroll
      for (int mt = 0; mt < 2; ++mt)
#pragma unroll
        for (int j = 0; j < 8; ++j)
          acc[mt][j] = mfma16(aa[c][mt], bb[c][j], acc[mt][j]);
    }
#pragma unroll
    for (int mt = 0; mt < 2; ++mt)
#pragma unroll
      for (int j = 0; j < 8; ++j)
#pragma unroll
        for (int r = 0; r < 4; ++r) {
          float v = acc[mt][j][r];
          v = v >= 0.f ? v : 0.01f * v;
          h2s[(mt * 16 + quad * 4 + r) * H2S + (wid * 8 + j) * 16 + l16] = (bf16_t)v;
        }
  }
  __syncthreads();

  // ---- stage 2: h3 = h2 @ w3 + b3 (M=32 K=512 N=512), then LayerNorm ----
  {
    f32x4 acc[2][8];
#pragma unroll
    for (int j = 0; j < 8; ++j) {
      float bc = b3[(wid * 8 + j) * 16 + l16];
      f32x4 z = {bc, bc, bc, bc};
      acc[0][j] = z; acc[1][j] = z;
    }
    const bf16x8* wf = (const bf16x8*)w3p;
    bf16x8 bb[2][8], aa[2][2];
#pragma unroll
    for (int j = 0; j < 8; ++j) bb[0][j] = wf[(0 * 32 + wid * 8 + j) * 64 + lane];
#pragma unroll
    for (int mt = 0; mt < 2; ++mt)
      aa[0][mt] = *(const bf16x8*)&h2s[(mt * 16 + l16) * H2S + quad * 8];
#pragma unroll
    for (int s = 0; s < 16; ++s) {
      int c = s & 1, nx = c ^ 1;
      if (s < 15) {
#pragma unroll
        for (int j = 0; j < 8; ++j)
          bb[nx][j] = wf[((s + 1) * 32 + wid * 8 + j) * 64 + lane];
#pragma unroll
        for (int mt = 0; mt < 2; ++mt)
          aa[nx][mt] = *(const bf16x8*)&h2s[(mt * 16 + l16) * H2S + (s + 1) * 32 + quad * 8];
      }
#pragma unroll
      for (int mt = 0; mt < 2; ++mt)
#pragma unroll
        for (int j = 0; j < 8; ++j)
          acc[mt][j] = mfma16(aa[c][mt], bb[c][j], acc[mt][j]);
    }

    // --- LayerNorm over 512 cols. Wave holds cols wid*128..+127 for all 32
    // tokens. Token t=mt*16+quad*4+r lives in the 16 lanes of `quad`.
    float psum[2][4];
#pragma unroll
    for (int mt = 0; mt < 2; ++mt)
#pragma unroll
      for (int r = 0; r < 4; ++r) {
        float s = 0.f;
#pragma unroll
        for (int j = 0; j < 8; ++j) s += acc[mt][j][r];
#pragma unroll
        for (int off = 1; off < 16; off <<= 1) s += __shfl_xor(s, off, 64);
        psum[mt][r] = s;
      }
    if (l16 == 0)
#pragma unroll
      for (int mt = 0; mt < 2; ++mt)
#pragma unroll
        for (int r = 0; r < 4; ++r)
          red[(mt * 16 + quad * 4 + r) * 4 + wid] = psum[mt][r];
    __syncthreads();
    float mu[2][4];
#pragma unroll
    for (int mt = 0; mt < 2; ++mt)
#pragma unroll
      for (int r = 0; r < 4; ++r) {
        int t = mt * 16 + quad * 4 + r;
        mu[mt][r] = (red[t * 4] + red[t * 4 + 1] + red[t * 4 + 2] + red[t * 4 + 3]) * (1.f / HID);
      }
    __syncthreads();
#pragma unroll
    for (int mt = 0; mt < 2; ++mt)
#pragma unroll
      for (int r = 0; r < 4; ++r) {
        float s = 0.f;
#pragma unroll
        for (int j = 0; j < 8; ++j) {
          float d = acc[mt][j][r] - mu[mt][r];
          s += d * d;
        }
#pragma unroll
        for (int off = 1; off < 16; off <<= 1) s += __shfl_xor(s, off, 64);
        psum[mt][r] = s;
      }
    if (l16 == 0)
#pragma unroll
      for (int mt = 0; mt < 2; ++mt)
#pragma unroll
        for (int r = 0; r < 4; ++r)
          red[(mt * 16 + quad * 4 + r) * 4 + wid] = psum[mt][r];
    __syncthreads();
    float rs[2][4];
#pragma unroll
    for (int mt = 0; mt < 2; ++mt)
#pragma unroll
      for (int r = 0; r < 4; ++r) {
        int t = mt * 16 + quad * 4 + r;
        float var = (red[t * 4] + red[t * 4 + 1] + red[t * 4 + 2] + red[t * 4 + 3]) * (1.f / HID);
        rs[mt][r] = rsqrtf(var + EPS);
      }
    const float* gp = side ? lvg : lkg;
    const float* bp = side ? lvb : lkb;
    float gc[8], bc[8];
#pragma unroll
    for (int j = 0; j < 8; ++j) {
      int col = (wid * 8 + j) * 16 + l16;
      gc[j] = gp[col];
      bc[j] = bp[col];
    }
    // all waves are past their h2s reads (barriers above) — safe to overwrite
#pragma unroll
    for (int mt = 0; mt < 2; ++mt)
#pragma unroll
      for (int j = 0; j < 8; ++j)
#pragma unroll
        for (int r = 0; r < 4; ++r) {
          float v = (acc[mt][j][r] - mu[mt][r]) * rs[mt][r] * gc[j] + bc[j];
          h2s[(mt * 16 + quad * 4 + r) * H2S + (wid * 8 + j) * 16 + l16] = (bf16_t)v;
        }
  }
  __syncthreads();

  // ---- stage 3: kv = LN @ (wk|wv) + bias (M=32 K=512 N=256), fp32 out ----
  {
    const bf16_t* wp = side ? wvp : wkp;
    const float* bias = side ? bv : bk;
    f32x4 acc[2][4];
#pragma unroll
    for (int j = 0; j < 4; ++j) {
      float bcv = bias[(wid * 4 + j) * 16 + l16];
      f32x4 z = {bcv, bcv, bcv, bcv};
      acc[0][j] = z; acc[1][j] = z;
    }
    const bf16x8* wf = (const bf16x8*)wp;
    bf16x8 bb[2][4], aa[2][2];
#pragma unroll
    for (int j = 0; j < 4; ++j) bb[0][j] = wf[(0 * 16 + wid * 4 + j) * 64 + lane];
#pragma unroll
    for (int mt = 0; mt < 2; ++mt)
      aa[0][mt] = *(const bf16x8*)&h2s[(mt * 16 + l16) * H2S + quad * 8];
#pragma unroll
    for (int s = 0; s < 16; ++s) {
      int c = s & 1, nx = c ^ 1;
      if (s < 15) {
#pragma unroll
        for (int j = 0; j < 4; ++j)
          bb[nx][j] = wf[((s + 1) * 16 + wid * 4 + j) * 64 + lane];
#pragma unroll
        for (int mt = 0; mt < 2; ++mt)
          aa[nx][mt] = *(const bf16x8*)&h2s[(mt * 16 + l16) * H2S + (s + 1) * 32 + quad * 8];
      }
#pragma unroll
      for (int mt = 0; mt < 2; ++mt)
#pragma unroll
        for (int j = 0; j < 4; ++j)
          acc[mt][j] = mfma16(aa[c][mt], bb[c][j], acc[mt][j]);
    }
#pragma unroll
    for (int mt = 0; mt < 2; ++mt)
#pragma unroll
      for (int j = 0; j < 4; ++j)
#pragma unroll
        for (int r = 0; r < 4; ++r)
          kvp[(blockBase + mt * 16 + quad * 4 + r) * DIMQ + (wid * 4 + j) * 16 + l16] =
              acc[mt][j][r];
  }
}

// ---------------------------------------------------------------------------
// K4: flash attention partials (unchanged this round).
// ---------------------------------------------------------------------------
__global__ __launch_bounds__(128)
void attn_kernel(const float* __restrict__ qbuf, const float* __restrict__ kvp,
                 float* __restrict__ part) {
  __shared__ float kt[64 * 32];
  __shared__ float vt[64 * 32];
  const int tid = threadIdx.x;
  const int chunk = blockIdx.x, h = blockIdx.y, b = blockIdx.z;

  float qreg[2][32];
#pragma unroll
  for (int rr = 0; rr < 2; ++rr) {
    int r = tid + rr * 128;
    for (int d = 0; d < 32; ++d) qreg[rr][d] = qbuf[r * DIMQ + h * 32 + d];
  }
  float m[2] = {-1e30f, -1e30f};
  float l[2] = {0.f, 0.f};
  float o[2][32];
#pragma unroll
  for (int rr = 0; rr < 2; ++rr)
    for (int d = 0; d < 32; ++d) o[rr][d] = 0.f;

  const int kbase = (b * SEQ + chunk * 512) * DIMQ + h * 32;
  const int vbase = ((65536 + b * SEQ) + chunk * 512) * DIMQ + h * 32;

  for (int ntile = 0; ntile < 8; ++ntile) {
    for (int idx = tid; idx < 2048; idx += 128) {
      int row = idx >> 5, d = idx & 31;
      kt[idx] = kvp[kbase + (ntile * 64 + row) * DIMQ + d];
      vt[idx] = kvp[vbase + (ntile * 64 + row) * DIMQ + d];
    }
    __syncthreads();
    for (int nn = 0; nn < 64; ++nn) {
      float k8[32];
      {
        const float4* kr = (const float4*)(kt + nn * 32);
#pragma unroll
        for (int q4 = 0; q4 < 8; ++q4) {
          float4 t4 = kr[q4];
          k8[q4 * 4 + 0] = t4.x; k8[q4 * 4 + 1] = t4.y;
          k8[q4 * 4 + 2] = t4.z; k8[q4 * 4 + 3] = t4.w;
        }
      }
      float pc[2];
#pragma unroll
      for (int rr = 0; rr < 2; ++rr) {
        float e = 0.f;
#pragma unroll
        for (int d = 0; d < 32; ++d) e += qreg[rr][d] * k8[d];
        if (e > m[rr]) {
          float al = __expf(m[rr] - e);
          l[rr] *= al;
#pragma unroll
          for (int d = 0; d < 32; ++d) o[rr][d] *= al;
          m[rr] = e;
        }
        float p = __expf(e - m[rr]);
        l[rr] += p;
        pc[rr] = p;
      }
      {
        const float4* vr = (const float4*)(vt + nn * 32);
#pragma unroll
        for (int q4 = 0; q4 < 8; ++q4) {
          float4 t4 = vr[q4];
          int d = q4 * 4;
          o[0][d + 0] += pc[0] * t4.x; o[1][d + 0] += pc[1] * t4.x;
          o[0][d + 1] += pc[0] * t4.y; o[1][d + 1] += pc[1] * t4.y;
          o[0][d + 2] += pc[0] * t4.z; o[1][d + 2] += pc[1] * t4.z;
          o[0][d + 3] += pc[0] * t4.w; o[1][d + 3] += pc[1] * t4.w;
        }
      }
    }
    __syncthreads();
  }

  const int pb = (((b * 8 + h) * 8 + chunk) * 256) * 34;
#pragma unroll
  for (int rr = 0; rr < 2; ++rr) {
    int r = tid + rr * 128;
    float* p = part + pb + r * 34;
    p[0] = m[rr];
    p[1] = l[rr];
    for (int d = 0; d < 32; ++d) p[2 + d] = o[rr][d];
  }
}

// ---------------------------------------------------------------------------
// K5: combine chunk partials (unchanged).
// ---------------------------------------------------------------------------
__global__ __launch_bounds__(256)
void combine_kernel(const float* __restrict__ part, float* __restrict__ ao) {
  const int bh = blockIdx.x;
  const int r = threadIdx.x;
  const int b = bh >> 3, h = bh & 7;
  float M = -1e30f;
  for (int c = 0; c < 8; ++c)
    M = fmaxf(M, part[((bh * 8 + c) * 256 + r) * 34]);
  float L = 0.f;
  float o[32];
  for (int d = 0; d < 32; ++d) o[d] = 0.f;
  for (int c = 0; c < 8; ++c) {
    const float* p = part + ((bh * 8 + c) * 256 + r) * 34;
    float w = __expf(p[0] - M);
    L += p[1] * w;
    for (int d = 0; d < 32; ++d) o[d] += p[2 + d] * w;
  }
  float inv = 1.f / L;
  for (int d = 0; d < 32; ++d)
    ao[(b * 256 + r) * 256 + h * 32 + d] = o[d] * inv;
}

// ---------------------------------------------------------------------------
// K6: final projection (unchanged).
// ---------------------------------------------------------------------------
__global__ __launch_bounds__(256)
void outproj_kernel(const float* __restrict__ ao, const float* __restrict__ wo,
                    const float* __restrict__ bo, float* __restrict__ out) {
  __shared__ float At[16 * 256];
  const int tid = threadIdx.x;
  const int rb = blockIdx.x * 16;
  for (int idx = tid; idx < 16 * 256; idx += 256) At[idx] = ao[rb * 256 + idx];
  __syncthreads();
  float acc[16];
  float bj = bo[tid];
#pragma unroll
  for (int u = 0; u < 16; ++u) acc[u] = bj;
  for (int d = 0; d < 256; ++d) {
    float w = wo[d * 256 + tid];
#pragma unroll
    for (int u = 0; u < 16; ++u) acc[u] += At[u * 256 + d] * w;
  }
#pragma unroll
  for (int u = 0; u < 16; ++u) out[(rb + u) * 256 + tid] = acc[u];
}

// ---------------------------------------------------------------------------
extern "C" void kernel_launch(void* const* d_in, const int* in_sizes, int n_in,
                              void* d_out, int out_size, void* d_ws, size_t ws_size,
                              hipStream_t stream) {
  const float* input = (const float*)d_in[0];
  const float* qp    = (const float*)d_in[1];
  const float* w1    = (const float*)d_in[2];
  const float* b1    = (const float*)d_in[3];
  const float* w2    = (const float*)d_in[4];
  const float* b2    = (const float*)d_in[5];
  const float* w3    = (const float*)d_in[6];
  const float* b3    = (const float*)d_in[7];
  const float* lqg   = (const float*)d_in[8];
  const float* lqb   = (const float*)d_in[9];
  const float* lkg   = (const float*)d_in[10];
  const float* lkb   = (const float*)d_in[11];
  const float* lvg   = (const float*)d_in[12];
  const float* lvb   = (const float*)d_in[13];
  const float* wq    = (const float*)d_in[14];
  const float* bq    = (const float*)d_in[15];
  const float* wk    = (const float*)d_in[16];
  const float* bk    = (const float*)d_in[17];
  const float* wv    = (const float*)d_in[18];
  const float* bv    = (const float*)d_in[19];
  const float* wo    = (const float*)d_in[20];
  const float* bo    = (const float*)d_in[21];
  float* out = (float*)d_out;

  char* ws = (char*)d_ws;
  // kvp: 131072 x 256 fp32 (k tokens 0..65535, v tokens 65536..131071)
  float* kvp  = (float*)(ws);
  float* qbuf = (float*)(ws + 134217728);                       // 256 KB
  float* part = (float*)(ws + 134217728 + 262144);              // 35.65 MB
  float* ao   = (float*)(ws + 134217728 + 262144 + 35651584);   // 4 MB

  // Packed bf16 weights alias the `part` region: consumed by token_kernel,
  // which completes before attn_kernel writes part. 1.15 MB total.
  bf16_t* w2p = (bf16_t*)part;            //  65536 elems
  bf16_t* w3p = w2p + 65536;              // 262144 elems
  bf16_t* wkp = w3p + 262144;             // 131072 elems
  bf16_t* wvp = wkp + 131072;             // 131072 elems

  pack_kernel<<<256, 256, 0, stream>>>(w2, w2p, 128, HID);
  pack_kernel<<<1024, 256, 0, stream>>>(w3, w3p, HID, HID);
  pack_kernel<<<512, 256, 0, stream>>>(wk, wkp, HID, DIMQ);
  pack_kernel<<<512, 256, 0, stream>>>(wv, wvp, HID, DIMQ);

  qgen_kernel<<<256, 256, 0, stream>>>(qp, lqg, lqb, wq, bq, qbuf);
  token_kernel<<<4096, 256, 0, stream>>>(input, w1, b1, w2p, b2, w3p, b3,
                                         lkg, lkb, lvg, lvb,
                                         wkp, bk, wvp, bv, kvp);
  attn_kernel<<<dim3(8, 8, 16), 128, 0, stream>>>(qbuf, kvp, part);
  combine_kernel<<<128, 256, 0, stream>>>(part, ao);
  outproj_kernel<<<256, 256, 0, stream>>>(ao, wo, bo, out);
}

// Round 3
// 456.737 us; speedup vs baseline: 4.4792x; 1.5094x over previous
//
#include <hip/hip_runtime.h>
#include <hip/hip_bf16.h>
#include <math.h>

#define DIMQ 256
#define HID 512
#define SEQ 4096
#define EPS 1e-5f
// 1/sqrt(32) * log2(e): folded into q so softmax runs in exp2 domain.
#define QK_SCALE_L2E 0.2550029770770258f
#define CHUNKS 4
#define CTOK 1024

typedef __bf16 bf16_t;
typedef __bf16 bf16x8 __attribute__((ext_vector_type(8)));
typedef __bf16 bf16x2 __attribute__((ext_vector_type(2)));
typedef float  f32x4  __attribute__((ext_vector_type(4)));

__device__ __forceinline__ f32x4 mfma16(bf16x8 a, bf16x8 b, f32x4 c) {
  return __builtin_amdgcn_mfma_f32_16x16x32_bf16(a, b, c, 0, 0, 0);
}

__device__ __forceinline__ float wave_sum(float v) {
#pragma unroll
  for (int off = 1; off < 64; off <<= 1) v += __shfl_xor(v, off, 64);
  return v;
}

// ---------------------------------------------------------------------------
// Pack fp32 weight [K][N] into bf16 MFMA B-fragment order.
// ---------------------------------------------------------------------------
__global__ __launch_bounds__(256)
void pack_kernel(const float* __restrict__ w, bf16_t* __restrict__ out,
                 int K, int N) {
  int idx = blockIdx.x * 256 + threadIdx.x;
  if (idx >= K * N) return;
  int j = idx & 7;
  int L = (idx >> 3) & 63;
  int f = idx >> 9;
  int NT = N >> 4;
  int nt = f % NT;
  int s = f / NT;
  int k = s * 32 + (L >> 4) * 8 + j;
  int n = nt * 16 + (L & 15);
  out[idx] = (bf16_t)w[k * N + n];
}

// ---------------------------------------------------------------------------
// K0: Q = LN(query_param) @ wq + bq, scaled by 1/sqrt(32)*log2e.
// Output: bf16 packed in MFMA A-frag order: qbufp[h][mt][lane][8].
// ---------------------------------------------------------------------------
__global__ __launch_bounds__(256)
void qgen_kernel(const float* __restrict__ qp, const float* __restrict__ g,
                 const float* __restrict__ b, const float* __restrict__ wq,
                 const float* __restrict__ bq, bf16_t* __restrict__ qbufp) {
  __shared__ float row[DIMQ];
  __shared__ float red[4];
  const int i = blockIdx.x;   // q row
  const int t = threadIdx.x;  // col
  const int lane = t & 63, wid = t >> 6;

  float v = qp[i * DIMQ + t];
  float s = wave_sum(v);
  if (lane == 0) red[wid] = s;
  __syncthreads();
  float mean = (red[0] + red[1] + red[2] + red[3]) * (1.0f / DIMQ);
  float d = v - mean;
  float s2 = wave_sum(d * d);
  __syncthreads();
  if (lane == 0) red[wid] = s2;
  __syncthreads();
  float var = (red[0] + red[1] + red[2] + red[3]) * (1.0f / DIMQ);
  float rs = rsqrtf(var + EPS);
  row[t] = d * rs * g[t] + b[t];
  __syncthreads();

  float acc = bq[t];
  for (int dd = 0; dd < DIMQ; ++dd) acc += row[dd] * wq[dd * DIMQ + t];
  acc *= QK_SCALE_L2E;
  // pack: A[m=i&15][k = d 0..31] for head h = t>>5
  int h = t >> 5, dd = t & 31;
  int mt = i >> 4, m = i & 15;
  qbufp[(((h * 16 + mt) * 64) + (dd >> 3) * 16 + m) * 8 + (dd & 7)] = (bf16_t)acc;
}

// ---------------------------------------------------------------------------
// KF: fused per-token pipeline (MFMA). Epilogue now writes bf16:
//   k natural [h][b][tok][32], v transposed [h][b][32][tok].
// ---------------------------------------------------------------------------
#define TOK 32
#define H1S 136
#define H2S 520

__global__ __launch_bounds__(256, 2)
void token_kernel(const float* __restrict__ input,
                  const float* __restrict__ w1, const float* __restrict__ b1,
                  const bf16_t* __restrict__ w2p, const float* __restrict__ b2,
                  const bf16_t* __restrict__ w3p, const float* __restrict__ b3,
                  const float* __restrict__ lkg, const float* __restrict__ lkb,
                  const float* __restrict__ lvg, const float* __restrict__ lvb,
                  const bf16_t* __restrict__ wkp, const float* __restrict__ bk,
                  const bf16_t* __restrict__ wvp, const float* __restrict__ bv,
                  bf16_t* __restrict__ kout, bf16_t* __restrict__ vout) {
  __shared__ bf16_t h1s[TOK * H1S];
  __shared__ bf16_t h2s[TOK * H2S];
  __shared__ float red[TOK * 4];
  __shared__ float xs[TOK];

  const int tid = threadIdx.x;
  const int lane = tid & 63;
  const int wid = tid >> 6;
  const int quad = lane >> 4;
  const int l16 = lane & 15;
  const int blockBase = blockIdx.x * TOK;
  const int side = blockBase >> 16;

  if (tid < TOK) xs[tid] = input[((blockBase + tid) & 65535) * 2 + side];
  __syncthreads();

  for (int idx = tid; idx < TOK * 128; idx += 256) {
    int t = idx >> 7, i = idx & 127;
    float h = xs[t] * w1[i] + b1[i];
    h1s[t * H1S + i] = (bf16_t)(h >= 0.f ? h : 0.01f * h);
  }
  __syncthreads();

  // ---- stage 1: h2 = leaky(h1 @ w2 + b2) ----
  {
    f32x4 acc[2][8];
#pragma unroll
    for (int j = 0; j < 8; ++j) {
      float bc = b2[(wid * 8 + j) * 16 + l16];
      f32x4 z = {bc, bc, bc, bc};
      acc[0][j] = z; acc[1][j] = z;
    }
    const bf16x8* wf = (const bf16x8*)w2p;
    bf16x8 bb[2][8], aa[2][2];
#pragma unroll
    for (int j = 0; j < 8; ++j) bb[0][j] = wf[(wid * 8 + j) * 64 + lane];
#pragma unroll
    for (int mt = 0; mt < 2; ++mt)
      aa[0][mt] = *(const bf16x8*)&h1s[(mt * 16 + l16) * H1S + quad * 8];
#pragma unroll
    for (int s = 0; s < 4; ++s) {
      int c = s & 1, nx = c ^ 1;
      if (s < 3) {
#pragma unroll
        for (int j = 0; j < 8; ++j)
          bb[nx][j] = wf[((s + 1) * 32 + wid * 8 + j) * 64 + lane];
#pragma unroll
        for (int mt = 0; mt < 2; ++mt)
          aa[nx][mt] = *(const bf16x8*)&h1s[(mt * 16 + l16) * H1S + (s + 1) * 32 + quad * 8];
      }
#pragma unroll
      for (int mt = 0; mt < 2; ++mt)
#pragma unroll
        for (int j = 0; j < 8; ++j)
          acc[mt][j] = mfma16(aa[c][mt], bb[c][j], acc[mt][j]);
    }
#pragma unroll
    for (int mt = 0; mt < 2; ++mt)
#pragma unroll
      for (int j = 0; j < 8; ++j)
#pragma unroll
        for (int r = 0; r < 4; ++r) {
          float v = acc[mt][j][r];
          v = v >= 0.f ? v : 0.01f * v;
          h2s[(mt * 16 + quad * 4 + r) * H2S + (wid * 8 + j) * 16 + l16] = (bf16_t)v;
        }
  }
  __syncthreads();

  // ---- stage 2: h3 = h2 @ w3 + b3, then LayerNorm ----
  {
    f32x4 acc[2][8];
#pragma unroll
    for (int j = 0; j < 8; ++j) {
      float bc = b3[(wid * 8 + j) * 16 + l16];
      f32x4 z = {bc, bc, bc, bc};
      acc[0][j] = z; acc[1][j] = z;
    }
    const bf16x8* wf = (const bf16x8*)w3p;
    bf16x8 bb[2][8], aa[2][2];
#pragma unroll
    for (int j = 0; j < 8; ++j) bb[0][j] = wf[(wid * 8 + j) * 64 + lane];
#pragma unroll
    for (int mt = 0; mt < 2; ++mt)
      aa[0][mt] = *(const bf16x8*)&h2s[(mt * 16 + l16) * H2S + quad * 8];
#pragma unroll
    for (int s = 0; s < 16; ++s) {
      int c = s & 1, nx = c ^ 1;
      if (s < 15) {
#pragma unroll
        for (int j = 0; j < 8; ++j)
          bb[nx][j] = wf[((s + 1) * 32 + wid * 8 + j) * 64 + lane];
#pragma unroll
        for (int mt = 0; mt < 2; ++mt)
          aa[nx][mt] = *(const bf16x8*)&h2s[(mt * 16 + l16) * H2S + (s + 1) * 32 + quad * 8];
      }
#pragma unroll
      for (int mt = 0; mt < 2; ++mt)
#pragma unroll
        for (int j = 0; j < 8; ++j)
          acc[mt][j] = mfma16(aa[c][mt], bb[c][j], acc[mt][j]);
    }

    float psum[2][4];
#pragma unroll
    for (int mt = 0; mt < 2; ++mt)
#pragma unroll
      for (int r = 0; r < 4; ++r) {
        float s = 0.f;
#pragma unroll
        for (int j = 0; j < 8; ++j) s += acc[mt][j][r];
#pragma unroll
        for (int off = 1; off < 16; off <<= 1) s += __shfl_xor(s, off, 64);
        psum[mt][r] = s;
      }
    if (l16 == 0)
#pragma unroll
      for (int mt = 0; mt < 2; ++mt)
#pragma unroll
        for (int r = 0; r < 4; ++r)
          red[(mt * 16 + quad * 4 + r) * 4 + wid] = psum[mt][r];
    __syncthreads();
    float mu[2][4];
#pragma unroll
    for (int mt = 0; mt < 2; ++mt)
#pragma unroll
      for (int r = 0; r < 4; ++r) {
        int t = mt * 16 + quad * 4 + r;
        mu[mt][r] = (red[t * 4] + red[t * 4 + 1] + red[t * 4 + 2] + red[t * 4 + 3]) * (1.f / HID);
      }
    __syncthreads();
#pragma unroll
    for (int mt = 0; mt < 2; ++mt)
#pragma unroll
      for (int r = 0; r < 4; ++r) {
        float s = 0.f;
#pragma unroll
        for (int j = 0; j < 8; ++j) {
          float d = acc[mt][j][r] - mu[mt][r];
          s += d * d;
        }
#pragma unroll
        for (int off = 1; off < 16; off <<= 1) s += __shfl_xor(s, off, 64);
        psum[mt][r] = s;
      }
    if (l16 == 0)
#pragma unroll
      for (int mt = 0; mt < 2; ++mt)
#pragma unroll
        for (int r = 0; r < 4; ++r)
          red[(mt * 16 + quad * 4 + r) * 4 + wid] = psum[mt][r];
    __syncthreads();
    float rs[2][4];
#pragma unroll
    for (int mt = 0; mt < 2; ++mt)
#pragma unroll
      for (int r = 0; r < 4; ++r) {
        int t = mt * 16 + quad * 4 + r;
        float var = (red[t * 4] + red[t * 4 + 1] + red[t * 4 + 2] + red[t * 4 + 3]) * (1.f / HID);
        rs[mt][r] = rsqrtf(var + EPS);
      }
    const float* gp = side ? lvg : lkg;
    const float* bp = side ? lvb : lkb;
    float gc[8], bc[8];
#pragma unroll
    for (int j = 0; j < 8; ++j) {
      int col = (wid * 8 + j) * 16 + l16;
      gc[j] = gp[col];
      bc[j] = bp[col];
    }
#pragma unroll
    for (int mt = 0; mt < 2; ++mt)
#pragma unroll
      for (int j = 0; j < 8; ++j)
#pragma unroll
        for (int r = 0; r < 4; ++r) {
          float v = (acc[mt][j][r] - mu[mt][r]) * rs[mt][r] * gc[j] + bc[j];
          h2s[(mt * 16 + quad * 4 + r) * H2S + (wid * 8 + j) * 16 + l16] = (bf16_t)v;
        }
  }
  __syncthreads();

  // ---- stage 3: kv = LN @ (wk|wv) + bias -> bf16 k / vT layouts ----
  {
    const bf16_t* wp = side ? wvp : wkp;
    const float* bias = side ? bv : bk;
    f32x4 acc[2][4];
#pragma unroll
    for (int j = 0; j < 4; ++j) {
      float bcv = bias[(wid * 4 + j) * 16 + l16];
      f32x4 z = {bcv, bcv, bcv, bcv};
      acc[0][j] = z; acc[1][j] = z;
    }
    const bf16x8* wf = (const bf16x8*)wp;
    bf16x8 bb[2][4], aa[2][2];
#pragma unroll
    for (int j = 0; j < 4; ++j) bb[0][j] = wf[(wid * 4 + j) * 64 + lane];
#pragma unroll
    for (int mt = 0; mt < 2; ++mt)
      aa[0][mt] = *(const bf16x8*)&h2s[(mt * 16 + l16) * H2S + quad * 8];
#pragma unroll
    for (int s = 0; s < 16; ++s) {
      int c = s & 1, nx = c ^ 1;
      if (s < 15) {
#pragma unroll
        for (int j = 0; j < 4; ++j)
          bb[nx][j] = wf[((s + 1) * 16 + wid * 4 + j) * 64 + lane];
#pragma unroll
        for (int mt = 0; mt < 2; ++mt)
          aa[nx][mt] = *(const bf16x8*)&h2s[(mt * 16 + l16) * H2S + (s + 1) * 32 + quad * 8];
      }
#pragma unroll
      for (int mt = 0; mt < 2; ++mt)
#pragma unroll
        for (int j = 0; j < 4; ++j)
          acc[mt][j] = mfma16(aa[c][mt], bb[c][j], acc[mt][j]);
    }
    const int tloc = blockBase & 65535;
    const int bb2 = tloc >> 12;
    const int n0 = tloc & 4095;
    if (side == 0) {
#pragma unroll
      for (int mt = 0; mt < 2; ++mt)
#pragma unroll
        for (int j = 0; j < 4; ++j) {
          int col = (wid * 4 + j) * 16 + l16;
          int hh = col >> 5, d = col & 31;
          bf16_t* o = kout + (size_t)(hh * 16 + bb2) * 4096 * 32;
#pragma unroll
          for (int r = 0; r < 4; ++r) {
            int n = n0 + mt * 16 + quad * 4 + r;
            o[(size_t)n * 32 + d] = (bf16_t)acc[mt][j][r];
          }
        }
    } else {
#pragma unroll
      for (int mt = 0; mt < 2; ++mt)
#pragma unroll
        for (int j = 0; j < 4; ++j) {
          int col = (wid * 4 + j) * 16 + l16;
          int hh = col >> 5, d = col & 31;
          bf16_t* o = vout + ((size_t)(hh * 16 + bb2) * 32 + d) * 4096;
#pragma unroll
          for (int r = 0; r < 4; ++r) {
            int n = n0 + mt * 16 + quad * 4 + r;
            o[n] = (bf16_t)acc[mt][j][r];
          }
        }
    }
  }
}

// ---------------------------------------------------------------------------
// K4: MFMA flash attention. grid (chunk=4, h=8, b=16), block 256 (4 waves).
// Wave w owns q rows w*64..w*64+63 (4 m-tiles), loops 1024 tokens in 32-tiles.
// K B-frags and V^T B-frags load 16B/lane direct from global; P transposes
// C-layout->A-layout via wave-private LDS (no barriers anywhere).
// Token interleave: S0 covers tok=2*l16, S1 tok=2*l16+1 -> P pair packs to
// one ds_write_b32 (2-way bank aliasing only).
// ---------------------------------------------------------------------------
__global__ __launch_bounds__(256, 4)
void attn_kernel(const bf16_t* __restrict__ qbufp,
                 const bf16_t* __restrict__ kb,
                 const bf16_t* __restrict__ vtb,
                 float* __restrict__ part) {
  __shared__ ushort p_lds[4][16 * 40];   // per-wave [16 q][40 tok-stride]
  const int tid = threadIdx.x;
  const int lane = tid & 63;
  const int w = tid >> 6;
  const int quad = lane >> 4;
  const int l16 = lane & 15;
  const int chunk = blockIdx.x, h = blockIdx.y, b = blockIdx.z;

  const bf16_t* kbase = kb + ((size_t)(h * 16 + b) * 4096 + chunk * CTOK) * 32;
  const bf16_t* kl0 = kbase + (2 * l16) * 32 + quad * 8;   // even tokens
  const bf16_t* kl1 = kl0 + 32;                            // odd tokens
  const bf16_t* vbase = vtb + (size_t)(h * 16 + b) * 32 * 4096 + chunk * CTOK;
  const bf16_t* vl0 = vbase + (size_t)l16 * 4096 + quad * 8;
  const bf16_t* vl1 = vl0 + (size_t)16 * 4096;
  const bf16_t* q_h = qbufp + (size_t)h * 16 * 64 * 8;

  ushort* pl = p_lds[w];
  uint* plw = (uint*)p_lds[w];
  const int prd = l16 * 40 + quad * 8;   // A-frag read offset (ushorts)

#pragma unroll 1
  for (int i = 0; i < 4; ++i) {
    const int mtg = w * 4 + i;
    bf16x8 qf = *(const bf16x8*)(q_h + ((size_t)mtg * 64 + lane) * 8);
    f32x4 O0 = {0.f, 0.f, 0.f, 0.f}, O1 = {0.f, 0.f, 0.f, 0.f};
    float mrow[4] = {-1e30f, -1e30f, -1e30f, -1e30f};
    float lrow[4] = {0.f, 0.f, 0.f, 0.f};

    bf16x8 kf0 = *(const bf16x8*)(kl0);
    bf16x8 kf1 = *(const bf16x8*)(kl1);
    bf16x8 vf0 = *(const bf16x8*)(vl0);
    bf16x8 vf1 = *(const bf16x8*)(vl1);

#pragma unroll 1
    for (int tt = 0; tt < 32; ++tt) {
      bf16x8 ck0 = kf0, ck1 = kf1, cv0 = vf0, cv1 = vf1;
      if (tt < 31) {
        int toff = (tt + 1) * 32;
        kf0 = *(const bf16x8*)(kl0 + (size_t)toff * 32);
        kf1 = *(const bf16x8*)(kl1 + (size_t)toff * 32);
        vf0 = *(const bf16x8*)(vl0 + toff);
        vf1 = *(const bf16x8*)(vl1 + toff);
      }
      f32x4 zero = {0.f, 0.f, 0.f, 0.f};
      f32x4 S0 = mfma16(qf, ck0, zero);
      f32x4 S1 = mfma16(qf, ck1, zero);

      float p0[4], p1[4], alpha[4];
#pragma unroll
      for (int r = 0; r < 4; ++r) {
        float rm = fmaxf(S0[r], S1[r]);
        rm = fmaxf(rm, __shfl_xor(rm, 1, 64));
        rm = fmaxf(rm, __shfl_xor(rm, 2, 64));
        rm = fmaxf(rm, __shfl_xor(rm, 4, 64));
        rm = fmaxf(rm, __shfl_xor(rm, 8, 64));
        float mn = fmaxf(mrow[r], rm);
        alpha[r] = __builtin_amdgcn_exp2f(mrow[r] - mn);
        mrow[r] = mn;
        p0[r] = __builtin_amdgcn_exp2f(S0[r] - mn);
        p1[r] = __builtin_amdgcn_exp2f(S1[r] - mn);
        float rs = p0[r] + p1[r];
        rs += __shfl_xor(rs, 1, 64);
        rs += __shfl_xor(rs, 2, 64);
        rs += __shfl_xor(rs, 4, 64);
        rs += __shfl_xor(rs, 8, 64);
        lrow[r] = lrow[r] * alpha[r] + rs;
      }
#pragma unroll
      for (int r = 0; r < 4; ++r) {
        O0[r] *= alpha[r];
        O1[r] *= alpha[r];
      }
#pragma unroll
      for (int r = 0; r < 4; ++r) {
        union { bf16x2 v; uint u; } pk;
        pk.v = (bf16x2){(bf16_t)p0[r], (bf16_t)p1[r]};
        plw[(quad * 4 + r) * 20 + l16] = pk.u;
      }
      bf16x8 pf = *(const bf16x8*)(pl + prd);
      O0 = mfma16(pf, cv0, O0);
      O1 = mfma16(pf, cv1, O1);
    }

    float* pb = part + (((size_t)(b * 8 + h) * CHUNKS + chunk) * 256 +
                        (w * 64 + i * 16)) * 34;
#pragma unroll
    for (int r = 0; r < 4; ++r) {
      float* pr = pb + (quad * 4 + r) * 34;
      pr[2 + l16] = O0[r];
      pr[18 + l16] = O1[r];
      if (l16 == 0) { pr[0] = mrow[r]; pr[1] = lrow[r]; }
    }
  }
}

// ---------------------------------------------------------------------------
// K5: combine chunk partials (exp2 domain).
// ---------------------------------------------------------------------------
__global__ __launch_bounds__(256)
void combine_kernel(const float* __restrict__ part, float* __restrict__ ao) {
  const int bh = blockIdx.x;
  const int r = threadIdx.x;
  const int b = bh >> 3, h = bh & 7;
  float M = -1e30f;
  for (int c = 0; c < CHUNKS; ++c)
    M = fmaxf(M, part[((size_t)(bh * CHUNKS + c) * 256 + r) * 34]);
  float L = 0.f;
  float o[32];
  for (int d = 0; d < 32; ++d) o[d] = 0.f;
  for (int c = 0; c < CHUNKS; ++c) {
    const float* p = part + ((size_t)(bh * CHUNKS + c) * 256 + r) * 34;
    float wgt = __builtin_amdgcn_exp2f(p[0] - M);
    L += p[1] * wgt;
    for (int d = 0; d < 32; ++d) o[d] += p[2 + d] * wgt;
  }
  float inv = 1.f / L;
  for (int d = 0; d < 32; ++d)
    ao[((size_t)b * 256 + r) * 256 + h * 32 + d] = o[d] * inv;
}

// ---------------------------------------------------------------------------
// K6: final projection out = ao @ wo + bo.
// ---------------------------------------------------------------------------
__global__ __launch_bounds__(256)
void outproj_kernel(const float* __restrict__ ao, const float* __restrict__ wo,
                    const float* __restrict__ bo, float* __restrict__ out) {
  __shared__ float At[16 * 256];
  const int tid = threadIdx.x;
  const int rb = blockIdx.x * 16;
  for (int idx = tid; idx < 16 * 256; idx += 256) At[idx] = ao[rb * 256 + idx];
  __syncthreads();
  float acc[16];
  float bj = bo[tid];
#pragma unroll
  for (int u = 0; u < 16; ++u) acc[u] = bj;
  for (int d = 0; d < 256; ++d) {
    float w = wo[d * 256 + tid];
#pragma unroll
    for (int u = 0; u < 16; ++u) acc[u] += At[u * 256 + d] * w;
  }
#pragma unroll
  for (int u = 0; u < 16; ++u) out[(rb + u) * 256 + tid] = acc[u];
}

// ---------------------------------------------------------------------------
extern "C" void kernel_launch(void* const* d_in, const int* in_sizes, int n_in,
                              void* d_out, int out_size, void* d_ws, size_t ws_size,
                              hipStream_t stream) {
  const float* input = (const float*)d_in[0];
  const float* qp    = (const float*)d_in[1];
  const float* w1    = (const float*)d_in[2];
  const float* b1    = (const float*)d_in[3];
  const float* w2    = (const float*)d_in[4];
  const float* b2    = (const float*)d_in[5];
  const float* w3    = (const float*)d_in[6];
  const float* b3    = (const float*)d_in[7];
  const float* lqg   = (const float*)d_in[8];
  const float* lqb   = (const float*)d_in[9];
  const float* lkg   = (const float*)d_in[10];
  const float* lkb   = (const float*)d_in[11];
  const float* lvg   = (const float*)d_in[12];
  const float* lvb   = (const float*)d_in[13];
  const float* wq    = (const float*)d_in[14];
  const float* bq    = (const float*)d_in[15];
  const float* wk    = (const float*)d_in[16];
  const float* bk    = (const float*)d_in[17];
  const float* wv    = (const float*)d_in[18];
  const float* bv    = (const float*)d_in[19];
  const float* wo    = (const float*)d_in[20];
  const float* bo    = (const float*)d_in[21];
  float* out = (float*)d_out;

  char* ws = (char*)d_ws;
  bf16_t* kout  = (bf16_t*)(ws);                 // 33,554,432 B
  bf16_t* vout  = (bf16_t*)(ws + 33554432);      // 33,554,432 B
  bf16_t* qbufp = (bf16_t*)(ws + 67108864);      //    131,072 B (pad to 256K)
  float*  part  = (float*) (ws + 67371008);      // 17,825,792 B
  float*  ao    = (float*) (ws + 85196800);      //  4,194,304 B
  bf16_t* w2p   = (bf16_t*)(ws + 89391104);      //  1,179,648 B packed weights
  bf16_t* w3p = w2p + 65536;
  bf16_t* wkp = w3p + 262144;
  bf16_t* wvp = wkp + 131072;

  pack_kernel<<<256, 256, 0, stream>>>(w2, w2p, 128, HID);
  pack_kernel<<<1024, 256, 0, stream>>>(w3, w3p, HID, HID);
  pack_kernel<<<512, 256, 0, stream>>>(wk, wkp, HID, DIMQ);
  pack_kernel<<<512, 256, 0, stream>>>(wv, wvp, HID, DIMQ);

  qgen_kernel<<<256, 256, 0, stream>>>(qp, lqg, lqb, wq, bq, qbufp);
  token_kernel<<<4096, 256, 0, stream>>>(input, w1, b1, w2p, b2, w3p, b3,
                                         lkg, lkb, lvg, lvb,
                                         wkp, bk, wvp, bv, kout, vout);
  attn_kernel<<<dim3(CHUNKS, 8, 16), 256, 0, stream>>>(qbufp, kout, vout, part);
  combine_kernel<<<128, 256, 0, stream>>>(part, ao);
  outproj_kernel<<<256, 256, 0, stream>>>(ao, wo, bo, out);
}

// Round 5
// 371.866 us; speedup vs baseline: 5.5015x; 1.2282x over previous
//
#include <hip/hip_runtime.h>
#include <hip/hip_bf16.h>
#include <math.h>

#define DIMQ 256
#define HID 512
#define SEQ 4096
#define EPS 1e-5f
// 1/sqrt(32) * log2(e): folded into q so softmax runs in exp2 domain.
#define QK_SCALE_L2E 0.2550029770770258f
#define CHUNKS 8
#define CTOK 512

typedef __bf16 bf16_t;
typedef __bf16 bf16x8 __attribute__((ext_vector_type(8)));
typedef float  f32x4  __attribute__((ext_vector_type(4)));

__device__ __forceinline__ f32x4 mfma16(bf16x8 a, bf16x8 b, f32x4 c) {
  return __builtin_amdgcn_mfma_f32_16x16x32_bf16(a, b, c, 0, 0, 0);
}

__device__ __forceinline__ float wave_sum(float v) {
#pragma unroll
  for (int off = 1; off < 64; off <<= 1) v += __shfl_xor(v, off, 64);
  return v;
}

// ---------------------------------------------------------------------------
// Pack fp32 weight [K][N] into bf16 MFMA B-fragment order (round-3-proven).
// ---------------------------------------------------------------------------
__global__ __launch_bounds__(256)
void pack_kernel(const float* __restrict__ w, bf16_t* __restrict__ out,
                 int K, int N) {
  int idx = blockIdx.x * 256 + threadIdx.x;
  if (idx >= K * N) return;
  int j = idx & 7;
  int L = (idx >> 3) & 63;
  int f = idx >> 9;
  int NT = N >> 4;
  int nt = f % NT;
  int s = f / NT;
  int k = s * 32 + (L >> 4) * 8 + j;
  int n = nt * 16 + (L & 15);
  out[idx] = (bf16_t)w[k * N + n];
}

// ---------------------------------------------------------------------------
// K0: Q = LN(query_param) @ wq + bq, scaled by 1/sqrt(32)*log2e.
// Output: bf16 packed in MFMA frag order qbufp[h][mt][lane][8].
// ---------------------------------------------------------------------------
__global__ __launch_bounds__(256)
void qgen_kernel(const float* __restrict__ qp, const float* __restrict__ g,
                 const float* __restrict__ b, const float* __restrict__ wq,
                 const float* __restrict__ bq, bf16_t* __restrict__ qbufp) {
  __shared__ float row[DIMQ];
  __shared__ float red[4];
  const int i = blockIdx.x;   // q row
  const int t = threadIdx.x;  // col
  const int lane = t & 63, wid = t >> 6;

  float v = qp[i * DIMQ + t];
  float s = wave_sum(v);
  if (lane == 0) red[wid] = s;
  __syncthreads();
  float mean = (red[0] + red[1] + red[2] + red[3]) * (1.0f / DIMQ);
  float d = v - mean;
  float s2 = wave_sum(d * d);
  __syncthreads();
  if (lane == 0) red[wid] = s2;
  __syncthreads();
  float var = (red[0] + red[1] + red[2] + red[3]) * (1.0f / DIMQ);
  float rs = rsqrtf(var + EPS);
  row[t] = d * rs * g[t] + b[t];
  __syncthreads();

  float acc = bq[t];
  for (int dd = 0; dd < DIMQ; ++dd) acc += row[dd] * wq[dd * DIMQ + t];
  acc *= QK_SCALE_L2E;
  int h = t >> 5, dd = t & 31;
  int mt = i >> 4, m = i & 15;
  qbufp[(((h * 16 + mt) * 64) + (dd >> 3) * 16 + m) * 8 + (dd & 7)] = (bf16_t)acc;
}

// ---------------------------------------------------------------------------
// KF: fused per-token pipeline (MFMA) — round-3-exact (passing version).
// ---------------------------------------------------------------------------
#define TOK 32
#define H1S 136
#define H2S 520

__global__ __launch_bounds__(256, 2)
void token_kernel(const float* __restrict__ input,
                  const float* __restrict__ w1, const float* __restrict__ b1,
                  const bf16_t* __restrict__ w2p, const float* __restrict__ b2,
                  const bf16_t* __restrict__ w3p, const float* __restrict__ b3,
                  const float* __restrict__ lkg, const float* __restrict__ lkb,
                  const float* __restrict__ lvg, const float* __restrict__ lvb,
                  const bf16_t* __restrict__ wkp, const float* __restrict__ bk,
                  const bf16_t* __restrict__ wvp, const float* __restrict__ bv,
                  bf16_t* __restrict__ kout, bf16_t* __restrict__ vout) {
  __shared__ bf16_t h1s[TOK * H1S];
  __shared__ bf16_t h2s[TOK * H2S];
  __shared__ float red[TOK * 4];
  __shared__ float xs[TOK];

  const int tid = threadIdx.x;
  const int lane = tid & 63;
  const int wid = tid >> 6;
  const int quad = lane >> 4;
  const int l16 = lane & 15;
  const int blockBase = blockIdx.x * TOK;
  const int side = blockBase >> 16;

  if (tid < TOK) xs[tid] = input[((blockBase + tid) & 65535) * 2 + side];
  __syncthreads();

  for (int idx = tid; idx < TOK * 128; idx += 256) {
    int t = idx >> 7, i = idx & 127;
    float h = xs[t] * w1[i] + b1[i];
    h1s[t * H1S + i] = (bf16_t)(h >= 0.f ? h : 0.01f * h);
  }
  __syncthreads();

  // ---- stage 1: h2 = leaky(h1 @ w2 + b2) ----
  {
    f32x4 acc[2][8];
#pragma unroll
    for (int j = 0; j < 8; ++j) {
      float bc = b2[(wid * 8 + j) * 16 + l16];
      f32x4 z = {bc, bc, bc, bc};
      acc[0][j] = z; acc[1][j] = z;
    }
    const bf16x8* wf = (const bf16x8*)w2p;
    bf16x8 bb[2][8], aa[2][2];
#pragma unroll
    for (int j = 0; j < 8; ++j) bb[0][j] = wf[(wid * 8 + j) * 64 + lane];
#pragma unroll
    for (int mt = 0; mt < 2; ++mt)
      aa[0][mt] = *(const bf16x8*)&h1s[(mt * 16 + l16) * H1S + quad * 8];
#pragma unroll
    for (int s = 0; s < 4; ++s) {
      int c = s & 1, nx = c ^ 1;
      if (s < 3) {
#pragma unroll
        for (int j = 0; j < 8; ++j)
          bb[nx][j] = wf[((s + 1) * 32 + wid * 8 + j) * 64 + lane];
#pragma unroll
        for (int mt = 0; mt < 2; ++mt)
          aa[nx][mt] = *(const bf16x8*)&h1s[(mt * 16 + l16) * H1S + (s + 1) * 32 + quad * 8];
      }
#pragma unroll
      for (int mt = 0; mt < 2; ++mt)
#pragma unroll
        for (int j = 0; j < 8; ++j)
          acc[mt][j] = mfma16(aa[c][mt], bb[c][j], acc[mt][j]);
    }
#pragma unroll
    for (int mt = 0; mt < 2; ++mt)
#pragma unroll
      for (int j = 0; j < 8; ++j)
#pragma unroll
        for (int r = 0; r < 4; ++r) {
          float v = acc[mt][j][r];
          v = v >= 0.f ? v : 0.01f * v;
          h2s[(mt * 16 + quad * 4 + r) * H2S + (wid * 8 + j) * 16 + l16] = (bf16_t)v;
        }
  }
  __syncthreads();

  // ---- stage 2: h3 = h2 @ w3 + b3, then LayerNorm ----
  {
    f32x4 acc[2][8];
#pragma unroll
    for (int j = 0; j < 8; ++j) {
      float bc = b3[(wid * 8 + j) * 16 + l16];
      f32x4 z = {bc, bc, bc, bc};
      acc[0][j] = z; acc[1][j] = z;
    }
    const bf16x8* wf = (const bf16x8*)w3p;
    bf16x8 bb[2][8], aa[2][2];
#pragma unroll
    for (int j = 0; j < 8; ++j) bb[0][j] = wf[(wid * 8 + j) * 64 + lane];
#pragma unroll
    for (int mt = 0; mt < 2; ++mt)
      aa[0][mt] = *(const bf16x8*)&h2s[(mt * 16 + l16) * H2S + quad * 8];
#pragma unroll
    for (int s = 0; s < 16; ++s) {
      int c = s & 1, nx = c ^ 1;
      if (s < 15) {
#pragma unroll
        for (int j = 0; j < 8; ++j)
          bb[nx][j] = wf[((s + 1) * 32 + wid * 8 + j) * 64 + lane];
#pragma unroll
        for (int mt = 0; mt < 2; ++mt)
          aa[nx][mt] = *(const bf16x8*)&h2s[(mt * 16 + l16) * H2S + (s + 1) * 32 + quad * 8];
      }
#pragma unroll
      for (int mt = 0; mt < 2; ++mt)
#pragma unroll
        for (int j = 0; j < 8; ++j)
          acc[mt][j] = mfma16(aa[c][mt], bb[c][j], acc[mt][j]);
    }

    float psum[2][4];
#pragma unroll
    for (int mt = 0; mt < 2; ++mt)
#pragma unroll
      for (int r = 0; r < 4; ++r) {
        float s = 0.f;
#pragma unroll
        for (int j = 0; j < 8; ++j) s += acc[mt][j][r];
#pragma unroll
        for (int off = 1; off < 16; off <<= 1) s += __shfl_xor(s, off, 64);
        psum[mt][r] = s;
      }
    if (l16 == 0)
#pragma unroll
      for (int mt = 0; mt < 2; ++mt)
#pragma unroll
        for (int r = 0; r < 4; ++r)
          red[(mt * 16 + quad * 4 + r) * 4 + wid] = psum[mt][r];
    __syncthreads();
    float mu[2][4];
#pragma unroll
    for (int mt = 0; mt < 2; ++mt)
#pragma unroll
      for (int r = 0; r < 4; ++r) {
        int t = mt * 16 + quad * 4 + r;
        mu[mt][r] = (red[t * 4] + red[t * 4 + 1] + red[t * 4 + 2] + red[t * 4 + 3]) * (1.f / HID);
      }
    __syncthreads();
#pragma unroll
    for (int mt = 0; mt < 2; ++mt)
#pragma unroll
      for (int r = 0; r < 4; ++r) {
        float s = 0.f;
#pragma unroll
        for (int j = 0; j < 8; ++j) {
          float d = acc[mt][j][r] - mu[mt][r];
          s += d * d;
        }
#pragma unroll
        for (int off = 1; off < 16; off <<= 1) s += __shfl_xor(s, off, 64);
        psum[mt][r] = s;
      }
    if (l16 == 0)
#pragma unroll
      for (int mt = 0; mt < 2; ++mt)
#pragma unroll
        for (int r = 0; r < 4; ++r)
          red[(mt * 16 + quad * 4 + r) * 4 + wid] = psum[mt][r];
    __syncthreads();
    float rs[2][4];
#pragma unroll
    for (int mt = 0; mt < 2; ++mt)
#pragma unroll
      for (int r = 0; r < 4; ++r) {
        int t = mt * 16 + quad * 4 + r;
        float var = (red[t * 4] + red[t * 4 + 1] + red[t * 4 + 2] + red[t * 4 + 3]) * (1.f / HID);
        rs[mt][r] = rsqrtf(var + EPS);
      }
    const float* gp = side ? lvg : lkg;
    const float* bp = side ? lvb : lkb;
    float gc[8], bc[8];
#pragma unroll
    for (int j = 0; j < 8; ++j) {
      int col = (wid * 8 + j) * 16 + l16;
      gc[j] = gp[col];
      bc[j] = bp[col];
    }
#pragma unroll
    for (int mt = 0; mt < 2; ++mt)
#pragma unroll
      for (int j = 0; j < 8; ++j)
#pragma unroll
        for (int r = 0; r < 4; ++r) {
          float v = (acc[mt][j][r] - mu[mt][r]) * rs[mt][r] * gc[j] + bc[j];
          h2s[(mt * 16 + quad * 4 + r) * H2S + (wid * 8 + j) * 16 + l16] = (bf16_t)v;
        }
  }
  __syncthreads();

  // ---- stage 3: kv = LN @ (wk|wv) + bias -> bf16 k / vT layouts ----
  {
    const bf16_t* wp = side ? wvp : wkp;
    const float* bias = side ? bv : bk;
    f32x4 acc[2][4];
#pragma unroll
    for (int j = 0; j < 4; ++j) {
      float bcv = bias[(wid * 4 + j) * 16 + l16];
      f32x4 z = {bcv, bcv, bcv, bcv};
      acc[0][j] = z; acc[1][j] = z;
    }
    const bf16x8* wf = (const bf16x8*)wp;
    bf16x8 bb[2][4], aa[2][2];
#pragma unroll
    for (int j = 0; j < 4; ++j) bb[0][j] = wf[(wid * 4 + j) * 64 + lane];
#pragma unroll
    for (int mt = 0; mt < 2; ++mt)
      aa[0][mt] = *(const bf16x8*)&h2s[(mt * 16 + l16) * H2S + quad * 8];
#pragma unroll
    for (int s = 0; s < 16; ++s) {
      int c = s & 1, nx = c ^ 1;
      if (s < 15) {
#pragma unroll
        for (int j = 0; j < 4; ++j)
          bb[nx][j] = wf[((s + 1) * 16 + wid * 4 + j) * 64 + lane];
#pragma unroll
        for (int mt = 0; mt < 2; ++mt)
          aa[nx][mt] = *(const bf16x8*)&h2s[(mt * 16 + l16) * H2S + (s + 1) * 32 + quad * 8];
      }
#pragma unroll
      for (int mt = 0; mt < 2; ++mt)
#pragma unroll
        for (int j = 0; j < 4; ++j)
          acc[mt][j] = mfma16(aa[c][mt], bb[c][j], acc[mt][j]);
    }
    const int tloc = blockBase & 65535;
    const int bb2 = tloc >> 12;
    const int n0 = tloc & 4095;
    if (side == 0) {
#pragma unroll
      for (int mt = 0; mt < 2; ++mt)
#pragma unroll
        for (int j = 0; j < 4; ++j) {
          int col = (wid * 4 + j) * 16 + l16;
          int hh = col >> 5, d = col & 31;
          bf16_t* o = kout + (size_t)(hh * 16 + bb2) * 4096 * 32;
#pragma unroll
          for (int r = 0; r < 4; ++r) {
            int n = n0 + mt * 16 + quad * 4 + r;
            o[(size_t)n * 32 + d] = (bf16_t)acc[mt][j][r];
          }
        }
    } else {
#pragma unroll
      for (int mt = 0; mt < 2; ++mt)
#pragma unroll
        for (int j = 0; j < 4; ++j) {
          int col = (wid * 4 + j) * 16 + l16;
          int hh = col >> 5, d = col & 31;
          bf16_t* o = vout + ((size_t)(hh * 16 + bb2) * 32 + d) * 4096;
#pragma unroll
          for (int r = 0; r < 4; ++r) {
            int n = n0 + mt * 16 + quad * 4 + r;
            o[n] = (bf16_t)acc[mt][j][r];
          }
        }
    }
  }
}

// ---------------------------------------------------------------------------
// K4: MFMA flash attention, transposed-S, ZERO LDS.
// S = mfma(A=K, B=Q): row = token, col = q. Lane(quad,l16) holds, for q=l16,
// scores of tokens quad*8+2r (S0[r]) and quad*8+2r+1 (S1[r]) — exactly the
// k-range (quad*8..quad*8+7) its PV A-fragment needs, so P packs entirely
// in-register. Alpha for O rows (q=quad*4+r) comes via __shfl. l is kept
// quad-local and reduced once at the end. tt outer / q-tile inner: K and V
// are read from global exactly once per block.
// ---------------------------------------------------------------------------
__global__ __launch_bounds__(256, 3)
void attn_kernel(const bf16_t* __restrict__ qbufp,
                 const bf16_t* __restrict__ kb,
                 const bf16_t* __restrict__ vtb,
                 float* __restrict__ part) {
  const int tid = threadIdx.x;
  const int lane = tid & 63;
  const int w = tid >> 6;
  const int quad = lane >> 4;
  const int l16 = lane & 15;
  const int chunk = blockIdx.x, h = blockIdx.y, b = blockIdx.z;

  // K A-frag: A[m=l16][k=quad*8+j] = K[tok=2*l16 (+1 for kf1)][d=quad*8+j]
  const bf16_t* ka = kb + (((size_t)(h * 16 + b) * 4096 + chunk * CTOK) + 2 * l16) * 32 + quad * 8;
  // V^T B-frag: B[k=quad*8+j][n=l16] = V[tok=quad*8+j][d=l16 (+16 for vl1)]
  const bf16_t* vl0 = vtb + ((size_t)(h * 16 + b) * 32 + l16) * 4096 + chunk * CTOK + quad * 8;
  const bf16_t* vl1 = vl0 + (size_t)16 * 4096;
  const bf16_t* q_h = qbufp + (size_t)h * 8192;

  bf16x8 qf[4];
#pragma unroll
  for (int i = 0; i < 4; ++i)
    qf[i] = *(const bf16x8*)(q_h + (size_t)((w * 4 + i) * 64 + lane) * 8);

  f32x4 O0[4], O1[4];
  float m[4], l[4];
#pragma unroll
  for (int i = 0; i < 4; ++i) {
    f32x4 z = {0.f, 0.f, 0.f, 0.f};
    O0[i] = z; O1[i] = z;
    m[i] = -1e30f; l[i] = 0.f;
  }

  bf16x8 kf0 = *(const bf16x8*)(ka);
  bf16x8 kf1 = *(const bf16x8*)(ka + 32);
  bf16x8 vf0 = *(const bf16x8*)(vl0);
  bf16x8 vf1 = *(const bf16x8*)(vl1);

#pragma unroll 1
  for (int tt = 0; tt < CTOK / 32; ++tt) {
    bf16x8 ck0 = kf0, ck1 = kf1, cv0 = vf0, cv1 = vf1;
    if (tt < CTOK / 32 - 1) {
      kf0 = *(const bf16x8*)(ka + (size_t)(tt + 1) * 1024);
      kf1 = *(const bf16x8*)(ka + (size_t)(tt + 1) * 1024 + 32);
      vf0 = *(const bf16x8*)(vl0 + (tt + 1) * 32);
      vf1 = *(const bf16x8*)(vl1 + (tt + 1) * 32);
    }
#pragma unroll
    for (int i = 0; i < 4; ++i) {
      f32x4 zero = {0.f, 0.f, 0.f, 0.f};
      f32x4 S0 = mfma16(ck0, qf[i], zero);   // rows = even toks, cols = q
      f32x4 S1 = mfma16(ck1, qf[i], zero);   // rows = odd  toks
      // column (q=l16) max over all 32 tokens: 8 in-lane + cross-quad
      float rm = fmaxf(fmaxf(fmaxf(S0[0], S0[1]), fmaxf(S0[2], S0[3])),
                       fmaxf(fmaxf(S1[0], S1[1]), fmaxf(S1[2], S1[3])));
      rm = fmaxf(rm, __shfl_xor(rm, 16, 64));
      rm = fmaxf(rm, __shfl_xor(rm, 32, 64));
      float mn = fmaxf(m[i], rm);
      float al = __builtin_amdgcn_exp2f(m[i] - mn);
      m[i] = mn;
      float p0[4], p1[4];
      float rs = 0.f;
#pragma unroll
      for (int r = 0; r < 4; ++r) {
        p0[r] = __builtin_amdgcn_exp2f(S0[r] - mn);
        p1[r] = __builtin_amdgcn_exp2f(S1[r] - mn);
        rs += p0[r] + p1[r];
      }
      l[i] = l[i] * al + rs;   // quad-local partial sum; reduced at end
      // P A-frag = this lane's own p values, k-ordered: tok quad*8+{0..7}
      bf16x8 pf;
      pf[0] = (bf16_t)p0[0]; pf[1] = (bf16_t)p1[0];
      pf[2] = (bf16_t)p0[1]; pf[3] = (bf16_t)p1[1];
      pf[4] = (bf16_t)p0[2]; pf[5] = (bf16_t)p1[2];
      pf[6] = (bf16_t)p0[3]; pf[7] = (bf16_t)p1[3];
      // alpha for O row q'=quad*4+r: fetch al from a lane with l16==q'
#pragma unroll
      for (int r = 0; r < 4; ++r) {
        float ar = __shfl(al, (lane & 48) | (quad * 4 + r), 64);
        O0[i][r] *= ar;
        O1[i][r] *= ar;
      }
      O0[i] = mfma16(pf, cv0, O0[i]);        // rows = q, cols = d 0..15
      O1[i] = mfma16(pf, cv1, O1[i]);        // cols = d 16..31
    }
  }

#pragma unroll
  for (int i = 0; i < 4; ++i) {
    float lt = l[i];
    lt += __shfl_xor(lt, 16, 64);
    lt += __shfl_xor(lt, 32, 64);
    float* pb = part + (((size_t)(b * 8 + h) * CHUNKS + chunk) * 256 +
                        (w * 4 + i) * 16) * 34;
#pragma unroll
    for (int r = 0; r < 4; ++r) {
      float* pr = pb + (quad * 4 + r) * 34;
      pr[2 + l16] = O0[i][r];
      pr[18 + l16] = O1[i][r];
    }
    if (quad == 0) {
      float* pr = pb + l16 * 34;
      pr[0] = m[i];
      pr[1] = lt;
    }
  }
}

// ---------------------------------------------------------------------------
// K5: combine chunk partials (exp2 domain).
// ---------------------------------------------------------------------------
__global__ __launch_bounds__(256)
void combine_kernel(const float* __restrict__ part, float* __restrict__ ao) {
  const int bh = blockIdx.x;
  const int r = threadIdx.x;
  const int b = bh >> 3, h = bh & 7;
  float M = -1e30f;
  for (int c = 0; c < CHUNKS; ++c)
    M = fmaxf(M, part[((size_t)(bh * CHUNKS + c) * 256 + r) * 34]);
  float L = 0.f;
  float o[32];
  for (int d = 0; d < 32; ++d) o[d] = 0.f;
  for (int c = 0; c < CHUNKS; ++c) {
    const float* p = part + ((size_t)(bh * CHUNKS + c) * 256 + r) * 34;
    float wgt = __builtin_amdgcn_exp2f(p[0] - M);
    L += p[1] * wgt;
    for (int d = 0; d < 32; ++d) o[d] += p[2 + d] * wgt;
  }
  float inv = 1.f / L;
  for (int d = 0; d < 32; ++d)
    ao[((size_t)b * 256 + r) * 256 + h * 32 + d] = o[d] * inv;
}

// ---------------------------------------------------------------------------
// K6: final projection out = ao @ wo + bo.
// ---------------------------------------------------------------------------
__global__ __launch_bounds__(256)
void outproj_kernel(const float* __restrict__ ao, const float* __restrict__ wo,
                    const float* __restrict__ bo, float* __restrict__ out) {
  __shared__ float At[16 * 256];
  const int tid = threadIdx.x;
  const int rb = blockIdx.x * 16;
  for (int idx = tid; idx < 16 * 256; idx += 256) At[idx] = ao[rb * 256 + idx];
  __syncthreads();
  float acc[16];
  float bj = bo[tid];
#pragma unroll
  for (int u = 0; u < 16; ++u) acc[u] = bj;
  for (int d = 0; d < 256; ++d) {
    float w = wo[d * 256 + tid];
#pragma unroll
    for (int u = 0; u < 16; ++u) acc[u] += At[u * 256 + d] * w;
  }
#pragma unroll
  for (int u = 0; u < 16; ++u) out[(rb + u) * 256 + tid] = acc[u];
}

// ---------------------------------------------------------------------------
extern "C" void kernel_launch(void* const* d_in, const int* in_sizes, int n_in,
                              void* d_out, int out_size, void* d_ws, size_t ws_size,
                              hipStream_t stream) {
  const float* input = (const float*)d_in[0];
  const float* qp    = (const float*)d_in[1];
  const float* w1    = (const float*)d_in[2];
  const float* b1    = (const float*)d_in[3];
  const float* w2    = (const float*)d_in[4];
  const float* b2    = (const float*)d_in[5];
  const float* w3    = (const float*)d_in[6];
  const float* b3    = (const float*)d_in[7];
  const float* lqg   = (const float*)d_in[8];
  const float* lqb   = (const float*)d_in[9];
  const float* lkg   = (const float*)d_in[10];
  const float* lkb   = (const float*)d_in[11];
  const float* lvg   = (const float*)d_in[12];
  const float* lvb   = (const float*)d_in[13];
  const float* wq    = (const float*)d_in[14];
  const float* bq    = (const float*)d_in[15];
  const float* wk    = (const float*)d_in[16];
  const float* bk    = (const float*)d_in[17];
  const float* wv    = (const float*)d_in[18];
  const float* bv    = (const float*)d_in[19];
  const float* wo    = (const float*)d_in[20];
  const float* bo    = (const float*)d_in[21];
  float* out = (float*)d_out;

  char* ws = (char*)d_ws;
  bf16_t* kout  = (bf16_t*)(ws);                  // 33,554,432 B
  bf16_t* vout  = (bf16_t*)(ws + 33554432);       // 33,554,432 B
  bf16_t* qbufp = (bf16_t*)(ws + 67108864);       //    262,144 B
  float*  part  = (float*) (ws + 67371008);       // 35,651,584 B (CHUNKS=8)
  float*  ao    = (float*) (ws + 103022592);      //  4,194,304 B
  bf16_t* wpk   = (bf16_t*)(ws + 107216896);      //  1,179,648 B
  bf16_t* w2p = wpk;
  bf16_t* w3p = w2p + 65536;
  bf16_t* wkp = w3p + 262144;
  bf16_t* wvp = wkp + 131072;

  pack_kernel<<<256, 256, 0, stream>>>(w2, w2p, 128, HID);
  pack_kernel<<<1024, 256, 0, stream>>>(w3, w3p, HID, HID);
  pack_kernel<<<512, 256, 0, stream>>>(wk, wkp, HID, DIMQ);
  pack_kernel<<<512, 256, 0, stream>>>(wv, wvp, HID, DIMQ);

  qgen_kernel<<<256, 256, 0, stream>>>(qp, lqg, lqb, wq, bq, qbufp);
  token_kernel<<<4096, 256, 0, stream>>>(input, w1, b1, w2p, b2, w3p, b3,
                                         lkg, lkb, lvg, lvb,
                                         wkp, bk, wvp, bv, kout, vout);
  attn_kernel<<<dim3(CHUNKS, 8, 16), 256, 0, stream>>>(qbufp, kout, vout, part);
  combine_kernel<<<128, 256, 0, stream>>>(part, ao);
  outproj_kernel<<<256, 256, 0, stream>>>(ao, wo, bo, out);
}